// Round 2
// baseline (571.578 us; speedup 1.0000x reference)
//
#include <hip/hip_runtime.h>
#include <hip/hip_bf16.h>

typedef short bf16x8 __attribute__((ext_vector_type(8)));
typedef float f32x4 __attribute__((ext_vector_type(4)));

constexpr int C_IN = 64, H_IN = 128, W_IN = 128, C_OUT = 128, OH = 126, OW = 126;
constexpr int PAD = 72;   // LDS row stride in bf16; 144B = 9 bank-groups -> consecutive rows rotate 16B-granule by 1 (conflict-free b128)
constexpr float SUBC = 0.7f;  // SUB1 + SUB2

// Reorder conv weights OIHW fp32 -> Wr[kh][kw][co][ci] bf16 (coalesced staging layout)
__global__ void reorder_weights(const float* __restrict__ w, __hip_bfloat16* __restrict__ wr) {
    int o = blockIdx.x * 256 + threadIdx.x;
    if (o >= 9 * C_OUT * C_IN) return;
    int ci = o & 63;
    int co = (o >> 6) & 127;
    int k9 = o >> 13;             // kh*3+kw
    int kh = k9 / 3, kw = k9 % 3;
    wr[o] = __float2bfloat16(w[((co * C_IN + ci) * 3 + kh) * 3 + kw]);
}

// One block per (n, oh): computes out[n][0..127][oh][0..125] via implicit GEMM
// M=128 (ow, padded from 126), N=128 (co), K=576 = (kh,kw) x ci
__global__ __launch_bounds__(256, 4) void conv_mish(
    const float* __restrict__ x, const __hip_bfloat16* __restrict__ wr,
    const float* __restrict__ bias, float* __restrict__ out)
{
    __shared__ __hip_bfloat16 Xs[128 * PAD];  // [w][ci]  input row, transposed
    __shared__ __hip_bfloat16 Bs[128 * PAD];  // [co][ci] weight slice for one (kh,kw)

    // XCD-aware swizzle: each XCD (b%8) gets a contiguous run of (n,oh) -> L2 row reuse
    int b = blockIdx.x;
    int lb = (b & 7) * 504 + (b >> 3);   // 4032 = 8 * 504
    int n  = lb / OH;
    int oh = lb % OH;

    int tid  = threadIdx.x;
    int lane = tid & 63;
    int wv   = tid >> 6;        // wave 0..3
    int wm   = wv >> 1;         // m-half (ow 0..63 / 64..127)
    int wn   = wv & 1;          // n-half (co 0..63 / 64..127)
    int quad = lane >> 4;
    int l16  = lane & 15;

    f32x4 acc[4][4] = {};

    const float* xn = x + (size_t)n * C_IN * H_IN * W_IN;

    for (int kh = 0; kh < 3; ++kh) {
        __syncthreads();  // previous iteration's Xs/Bs readers done before overwrite
        // ---- stage Xs[w][ci] = bf16(x[n][ci][oh+kh][w]) ----
        // register transpose: thread owns (w, ci-block of 8); 8 scalar global loads
        // (each 256B/wave coalesced), one bank-balanced ds_write_b128. Conflict-free.
        {
            int h = oh + kh;
            for (int r = 0; r < 4; ++r) {
                int t  = tid + r * 256;      // 0..1023
                int w  = t & 127;
                int cb = t >> 7;             // ci block 0..7
                const float* gp = xn + ((size_t)(cb * 8) * H_IN + h) * W_IN + w;
                alignas(16) __hip_bfloat16 tmp[8];
                #pragma unroll
                for (int e = 0; e < 8; ++e)
                    tmp[e] = __float2bfloat16(gp[(size_t)e * (H_IN * W_IN)]);
                *(bf16x8*)&Xs[w * PAD + cb * 8] = *(const bf16x8*)tmp;
            }
        }
        // ---- stage Bs[co][ci] for (kh, kw=0): 16B coalesced global + bank-balanced 16B LDS writes ----
        {
            const __hip_bfloat16* src = wr + ((kh * 3 + 0) << 13);
            for (int r = 0; r < 4; ++r) {
                int c   = tid + r * 256;     // chunk of 8 bf16
                int co  = c >> 3;
                int ci8 = (c & 7) << 3;
                *(bf16x8*)&Bs[co * PAD + ci8] = *(const bf16x8*)(src + co * 64 + ci8);
            }
        }
        __syncthreads();  // staging visible

        for (int kw = 0; kw < 3; ++kw) {
            if (kw) {
                __syncthreads();  // previous compute's Bs readers done
                const __hip_bfloat16* src = wr + ((kh * 3 + kw) << 13);
                for (int r = 0; r < 4; ++r) {
                    int c   = tid + r * 256;
                    int co  = c >> 3;
                    int ci8 = (c & 7) << 3;
                    *(bf16x8*)&Bs[co * PAD + ci8] = *(const bf16x8*)(src + co * 64 + ci8);
                }
                __syncthreads();  // staging visible
            }
            // ---- 2 K-steps of 32 (ci halves), 16 MFMA each per wave ----
            #pragma unroll
            for (int half = 0; half < 2; ++half) {
                int k0 = half * 32 + quad * 8;
                bf16x8 a[4], bf[4];
                #pragma unroll
                for (int j = 0; j < 4; ++j) {
                    int co = wn * 64 + j * 16 + l16;
                    bf[j] = *(const bf16x8*)&Bs[co * PAD + k0];
                }
                #pragma unroll
                for (int i = 0; i < 4; ++i) {
                    int m = wm * 64 + i * 16 + l16;
                    int widx = m + kw; if (widx > 127) widx = 127;  // pad rows read garbage, never stored
                    a[i] = *(const bf16x8*)&Xs[widx * PAD + k0];
                }
                #pragma unroll
                for (int i = 0; i < 4; ++i)
                    #pragma unroll
                    for (int j = 0; j < 4; ++j)
                        acc[i][j] = __builtin_amdgcn_mfma_f32_16x16x32_bf16(a[i], bf[j], acc[i][j], 0, 0, 0);
            }
        }
    }

    // ---- epilogue: bias - 0.7, Mish = v * tanh(softplus(v)) = v * t/(t+2), t = e*(e+2), e = exp(v) ----
    for (int j = 0; j < 4; ++j) {
        int co = wn * 64 + j * 16 + l16;
        float bb = bias[co] - SUBC;
        for (int i = 0; i < 4; ++i) {
            int ow0 = wm * 64 + i * 16 + quad * 4;   // <= 124 always
            float o[4];
            for (int r = 0; r < 4; ++r) {
                float v = acc[i][j][r] + bb;
                float e = __expf(v);
                float t = e * (e + 2.0f);
                float m = v * t * __builtin_amdgcn_rcpf(t + 2.0f);
                o[r] = (v > 20.0f) ? v : m;
            }
            float* dst = out + (((size_t)n * C_OUT + co) * OH + oh) * OW + ow0;
            float2 p0; p0.x = o[0]; p0.y = o[1];
            *(float2*)dst = p0;                       // ow0, ow0+1 <= 125: always valid
            if (ow0 + 2 < OW) {                       // skip only at ow0==124 (rows 126,127 are pad)
                float2 p1; p1.x = o[2]; p1.y = o[3];
                *(float2*)(dst + 2) = p1;
            }
        }
    }
}

extern "C" void kernel_launch(void* const* d_in, const int* in_sizes, int n_in,
                              void* d_out, int out_size, void* d_ws, size_t ws_size,
                              hipStream_t stream) {
    const float* x    = (const float*)d_in[0];
    const float* w    = (const float*)d_in[1];
    const float* bias = (const float*)d_in[2];
    float* out        = (float*)d_out;
    __hip_bfloat16* wr = (__hip_bfloat16*)d_ws;   // 9*128*64*2 = 147456 bytes

    reorder_weights<<<(9 * C_OUT * C_IN + 255) / 256, 256, 0, stream>>>(w, wr);
    conv_mish<<<32 * OH, 256, 0, stream>>>(x, wr, bias, out);
}

// Round 3
// 443.560 us; speedup vs baseline: 1.2886x; 1.2886x over previous
//
#include <hip/hip_runtime.h>
#include <hip/hip_bf16.h>

typedef short bf16x8 __attribute__((ext_vector_type(8)));
typedef float f32x4 __attribute__((ext_vector_type(4)));

constexpr int C_IN = 64, H_IN = 128, W_IN = 128, C_OUT = 128, OH = 126, OW = 126;
constexpr int PAD = 72;   // LDS row stride in bf16; 144B/row rotates 16B-granules by 1 per row -> conflict-free b128 reads
constexpr float SUBC = 0.7f;  // SUB1 + SUB2

// Reorder conv weights OIHW fp32 -> Wr[kh][kw][co][ci] bf16 (coalesced staging layout)
__global__ void reorder_weights(const float* __restrict__ w, __hip_bfloat16* __restrict__ wr) {
    int o = blockIdx.x * 256 + threadIdx.x;
    if (o >= 9 * C_OUT * C_IN) return;
    int ci = o & 63;
    int co = (o >> 6) & 127;
    int k9 = o >> 13;             // kh*3+kw
    int kh = k9 / 3, kw = k9 % 3;
    wr[o] = __float2bfloat16(w[((co * C_IN + ci) * 3 + kh) * 3 + kw]);
}

// One block per (n, oh): computes out[n][0..127][oh][0..125] via implicit GEMM
// M=128 (ow, padded from 126), N=128 (co), K=576 = (kh,kw) x ci
// launch_bounds(256,2): 256-reg unified budget -> NO spill (R1/R2 regression was (256,4) spilling to scratch)
__global__ __launch_bounds__(256, 2) void conv_mish(
    const float* __restrict__ x, const __hip_bfloat16* __restrict__ wr,
    const float* __restrict__ bias, float* __restrict__ out)
{
    __shared__ __hip_bfloat16 Xs[128 * PAD];  // [w][ci]  input row, transposed
    __shared__ __hip_bfloat16 Bs[128 * PAD];  // [co][ci] weight slice for one (kh,kw)

    // XCD-aware swizzle: each XCD (b%8) gets a contiguous run of (n,oh) -> L2 row reuse
    int b = blockIdx.x;
    int lb = (b & 7) * 504 + (b >> 3);   // 4032 = 8 * 504
    int n  = lb / OH;
    int oh = lb % OH;

    int tid  = threadIdx.x;
    int lane = tid & 63;
    int wv   = tid >> 6;        // wave 0..3
    int wm   = wv >> 1;         // m-half (ow 0..63 / 64..127)
    int wn   = wv & 1;          // n-half (co 0..63 / 64..127)
    int quad = lane >> 4;
    int l16  = lane & 15;

    f32x4 acc[4][4] = {};

    const float* xn = x + (size_t)n * C_IN * H_IN * W_IN;

    for (int kh = 0; kh < 3; ++kh) {
        __syncthreads();  // previous iteration's Xs/Bs readers done before overwrite
        // ---- stage Xs[w][ci] = bf16(x[n][ci][oh+kh][w]) ----
        // register transpose: thread owns (w, ci-block of 8); 8 scalar global loads
        // (each 256B/wave coalesced), one bank-balanced ds_write_b128. Conflict-free
        // (measured R1/R2: 5.6e7 -> 4.6e6 conflict cycles vs transposed scalar writes).
        {
            int h = oh + kh;
            for (int r = 0; r < 4; ++r) {
                int t  = tid + r * 256;      // 0..1023
                int w  = t & 127;
                int cb = t >> 7;             // ci block 0..7
                const float* gp = xn + ((size_t)(cb * 8) * H_IN + h) * W_IN + w;
                alignas(16) __hip_bfloat16 tmp[8];
                #pragma unroll
                for (int e = 0; e < 8; ++e)
                    tmp[e] = __float2bfloat16(gp[(size_t)e * (H_IN * W_IN)]);
                *(bf16x8*)&Xs[w * PAD + cb * 8] = *(const bf16x8*)tmp;
            }
        }
        // ---- stage Bs[co][ci] for (kh, kw=0): 16B coalesced global + bank-balanced 16B LDS writes ----
        {
            const __hip_bfloat16* src = wr + ((kh * 3 + 0) << 13);
            for (int r = 0; r < 4; ++r) {
                int c   = tid + r * 256;     // chunk of 8 bf16
                int co  = c >> 3;
                int ci8 = (c & 7) << 3;
                *(bf16x8*)&Bs[co * PAD + ci8] = *(const bf16x8*)(src + co * 64 + ci8);
            }
        }
        __syncthreads();  // staging visible

        for (int kw = 0; kw < 3; ++kw) {
            if (kw) {
                __syncthreads();  // previous compute's Bs readers done
                const __hip_bfloat16* src = wr + ((kh * 3 + kw) << 13);
                for (int r = 0; r < 4; ++r) {
                    int c   = tid + r * 256;
                    int co  = c >> 3;
                    int ci8 = (c & 7) << 3;
                    *(bf16x8*)&Bs[co * PAD + ci8] = *(const bf16x8*)(src + co * 64 + ci8);
                }
                __syncthreads();  // staging visible
            }
            // ---- 2 K-steps of 32 (ci halves), 16 MFMA each per wave ----
            #pragma unroll
            for (int half = 0; half < 2; ++half) {
                int k0 = half * 32 + quad * 8;
                bf16x8 a[4], bf[4];
                #pragma unroll
                for (int j = 0; j < 4; ++j) {
                    int co = wn * 64 + j * 16 + l16;
                    bf[j] = *(const bf16x8*)&Bs[co * PAD + k0];
                }
                #pragma unroll
                for (int i = 0; i < 4; ++i) {
                    int m = wm * 64 + i * 16 + l16;
                    int widx = m + kw; if (widx > 127) widx = 127;  // pad rows read garbage, never stored
                    a[i] = *(const bf16x8*)&Xs[widx * PAD + k0];
                }
                #pragma unroll
                for (int i = 0; i < 4; ++i)
                    #pragma unroll
                    for (int j = 0; j < 4; ++j)
                        acc[i][j] = __builtin_amdgcn_mfma_f32_16x16x32_bf16(a[i], bf[j], acc[i][j], 0, 0, 0);
            }
        }
    }

    // ---- epilogue: bias - 0.7, Mish = v * tanh(softplus(v)) = v * t/(t+2), t = e*(e+2), e = exp(v) ----
    for (int j = 0; j < 4; ++j) {
        int co = wn * 64 + j * 16 + l16;
        float bb = bias[co] - SUBC;
        for (int i = 0; i < 4; ++i) {
            int ow0 = wm * 64 + i * 16 + quad * 4;   // <= 124 always
            float o[4];
            for (int r = 0; r < 4; ++r) {
                float v = acc[i][j][r] + bb;
                float e = __expf(v);
                float t = e * (e + 2.0f);
                float m = v * t * __builtin_amdgcn_rcpf(t + 2.0f);
                o[r] = (v > 20.0f) ? v : m;
            }
            float* dst = out + (((size_t)n * C_OUT + co) * OH + oh) * OW + ow0;
            float2 p0; p0.x = o[0]; p0.y = o[1];
            *(float2*)dst = p0;                       // ow0, ow0+1 <= 125: always valid
            if (ow0 + 2 < OW) {                       // skip only at ow0==124 (rows 126,127 are pad)
                float2 p1; p1.x = o[2]; p1.y = o[3];
                *(float2*)(dst + 2) = p1;
            }
        }
    }
}

extern "C" void kernel_launch(void* const* d_in, const int* in_sizes, int n_in,
                              void* d_out, int out_size, void* d_ws, size_t ws_size,
                              hipStream_t stream) {
    const float* x    = (const float*)d_in[0];
    const float* w    = (const float*)d_in[1];
    const float* bias = (const float*)d_in[2];
    float* out        = (float*)d_out;
    __hip_bfloat16* wr = (__hip_bfloat16*)d_ws;   // 9*128*64*2 = 147456 bytes

    reorder_weights<<<(9 * C_OUT * C_IN + 255) / 256, 256, 0, stream>>>(w, wr);
    conv_mish<<<32 * OH, 256, 0, stream>>>(x, wr, bias, out);
}